// Round 1
// baseline (4579.297 us; speedup 1.0000x reference)
//
#include <hip/hip_runtime.h>
#include <hip/hip_bf16.h>

using bf16 = __hip_bfloat16;

__device__ __forceinline__ float bf2f(bf16 v) { return __bfloat162float(v); }

// ---------------- kernel 1: codebook argmin + extract c ----------------
__global__ void k_codebook(const float* __restrict__ emb, float* __restrict__ c) {
    __shared__ float sval[512];
    __shared__ int   sidx[512];
    int k = threadIdx.x;
    float s = 0.f;
    const float* e = emb + k * 128;
    for (int d = 0; d < 128; ++d) { float v = e[d]; s += v * v; }
    sval[k] = s; sidx[k] = k;
    __syncthreads();
    for (int off = 256; off > 0; off >>= 1) {
        if (k < off) {
            float v2 = sval[k + off]; int i2 = sidx[k + off];
            if (v2 < sval[k] || (v2 == sval[k] && i2 < sidx[k])) { sval[k] = v2; sidx[k] = i2; }
        }
        __syncthreads();
    }
    int kmin = sidx[0];
    if (k < 128) c[k] = emb[kmin * 128 + k];
}

// ---------------- kernel 2: conv1 (1->64, k4 s2 p1) + relu -> h1 bf16 ----------------
__global__ __launch_bounds__(256) void k_conv1(const float* __restrict__ x,
                                               const float* __restrict__ w,
                                               const float* __restrict__ bias,
                                               bf16* __restrict__ h1) {
    int s  = blockIdx.x * 256 + threadIdx.x;   // 0..12543 (112*112)
    int co = blockIdx.y;                        // 64
    int b  = blockIdx.z;                        // 32
    int oh = s / 112, ow = s % 112;
    float acc = bias[co];
    const float* xb = x + b * 224 * 224;
    const float* wc = w + co * 16;
    #pragma unroll
    for (int kh = 0; kh < 4; ++kh) {
        int ih = 2 * oh - 1 + kh;
        if ((unsigned)ih < 224u) {
            #pragma unroll
            for (int kw = 0; kw < 4; ++kw) {
                int iw = 2 * ow - 1 + kw;
                if ((unsigned)iw < 224u) acc += xb[ih * 224 + iw] * wc[kh * 4 + kw];
            }
        }
    }
    acc = fmaxf(acc, 0.f);
    h1[((b * 64 + co) * 112 + oh) * 112 + ow] = __float2bfloat16(acc);
}

// ---------------- kernel 3: conv2 (64->128, k4 s2 p1) + relu -> h2 bf16 ----------------
// block = 64 threads (1 wave) over ow; 16 output channels per block in registers.
__global__ __launch_bounds__(64) void k_conv2(const bf16* __restrict__ h1,
                                              const float* __restrict__ w,
                                              const float* __restrict__ bias,
                                              bf16* __restrict__ h2) {
    int ow  = threadIdx.x;       // active < 56
    int oh  = blockIdx.x;        // 56
    int cog = blockIdx.y;        // 8  -> co = cog*16 + j
    int b   = blockIdx.z;        // 32
    bool act = ow < 56;
    float acc[16];
    #pragma unroll
    for (int j = 0; j < 16; ++j) acc[j] = 0.f;
    const bf16*  hb = h1 + b * 64 * 112 * 112;
    const float* wb = w + cog * 16 * 64 * 16;   // [16co][64ci][4][4]
    for (int ci = 0; ci < 64; ++ci) {
        const bf16*  hc  = hb + ci * 112 * 112;
        const float* wci = wb + ci * 16;
        #pragma unroll
        for (int kh = 0; kh < 4; ++kh) {
            int ih = 2 * oh - 1 + kh;
            if ((unsigned)ih >= 112u) continue;
            #pragma unroll
            for (int kw = 0; kw < 4; ++kw) {
                int iw = 2 * ow - 1 + kw;
                float v = (act && (unsigned)iw < 112u) ? bf2f(hc[ih * 112 + iw]) : 0.f;
                #pragma unroll
                for (int j = 0; j < 16; ++j) acc[j] += v * wci[j * 1024 + kh * 4 + kw];
            }
        }
    }
    if (act) {
        int co0 = cog * 16;
        #pragma unroll
        for (int j = 0; j < 16; ++j) {
            float o = fmaxf(acc[j] + bias[co0 + j], 0.f);
            h2[((b * 128 + co0 + j) * 56 + oh) * 56 + ow] = __float2bfloat16(o);
        }
    }
}

// ---------------- kernel 4: conv3 (128->128, k3 s1 p1), fused vq-loss partial ----------------
// z_e never stored: accumulate (c[co]-z_e)^2 per block.
__global__ __launch_bounds__(64) void k_conv3_vq(const bf16* __restrict__ h2,
                                                 const float* __restrict__ w,
                                                 const float* __restrict__ bias,
                                                 const float* __restrict__ c,
                                                 float* __restrict__ vq_part) {
    int ow  = threadIdx.x;       // active < 56
    int oh  = blockIdx.x;        // 56
    int cog = blockIdx.y;        // 8
    int b   = blockIdx.z;        // 32
    bool act = ow < 56;
    float acc[16];
    #pragma unroll
    for (int j = 0; j < 16; ++j) acc[j] = 0.f;
    const bf16*  hb = h2 + b * 128 * 56 * 56;
    const float* wb = w + cog * 16 * 128 * 9;   // [16co][128ci][3][3]
    for (int ci = 0; ci < 128; ++ci) {
        const bf16*  hc  = hb + ci * 56 * 56;
        const float* wci = wb + ci * 9;
        #pragma unroll
        for (int kh = 0; kh < 3; ++kh) {
            int ih = oh - 1 + kh;
            if ((unsigned)ih >= 56u) continue;
            #pragma unroll
            for (int kw = 0; kw < 3; ++kw) {
                int iw = ow - 1 + kw;
                float v = (act && (unsigned)iw < 56u) ? bf2f(hc[ih * 56 + iw]) : 0.f;
                #pragma unroll
                for (int j = 0; j < 16; ++j) acc[j] += v * wci[j * 1152 + kh * 3 + kw];
            }
        }
    }
    float ls = 0.f;
    if (act) {
        int co0 = cog * 16;
        #pragma unroll
        for (int j = 0; j < 16; ++j) {
            float z = acc[j] + bias[co0 + j];
            float d = c[co0 + j] - z;
            ls += d * d;
        }
    }
    #pragma unroll
    for (int off = 32; off > 0; off >>= 1) ls += __shfl_down(ls, off);
    if (threadIdx.x == 0) vq_part[(b * 8 + cog) * 56 + oh] = ls;
}

// ---------------- kernel 5: S[co,kh,kw] = sum_ci w_d1[co,ci,kh,kw]*c[ci] ----------------
__global__ void k_S(const float* __restrict__ w_d1, const float* __restrict__ c,
                    float* __restrict__ S) {
    int khw = blockIdx.x;   // 0..8
    int co  = threadIdx.x;  // 128
    float s = 0.f;
    for (int ci = 0; ci < 128; ++ci) s += w_d1[(co * 128 + ci) * 9 + khw] * c[ci];
    S[co * 9 + khw] = s;
}

// ---------------- kernel 6: d[co,h,w] (conv of constant input; once, batch-indep) ----------------
__global__ __launch_bounds__(256) void k_d(const float* __restrict__ S,
                                           const float* __restrict__ bias,
                                           float* __restrict__ d) {
    int idx = blockIdx.x * 256 + threadIdx.x;  // < 401408
    int co = idx / 3136; int s = idx % 3136; int h = s / 56, w0 = s % 56;
    float a = bias[co];
    const float* Sc = S + co * 9;
    #pragma unroll
    for (int kh = 0; kh < 3; ++kh) {
        int ih = h - 1 + kh;
        if ((unsigned)ih >= 56u) continue;
        #pragma unroll
        for (int kw = 0; kw < 3; ++kw) {
            int iw = w0 - 1 + kw;
            if ((unsigned)iw < 56u) a += Sc[kh * 3 + kw];
        }
    }
    d[idx] = a;
}

// ---------------- kernel 7: d2 = relu(convT(d, w_dt1)) [64,112,112], once ----------------
__global__ __launch_bounds__(256) void k_d2(const float* __restrict__ d,
                                            const float* __restrict__ w,
                                            const float* __restrict__ bias,
                                            float* __restrict__ d2) {
    int s  = blockIdx.x * 256 + threadIdx.x;  // 0..12543
    int co = blockIdx.y;                      // 64
    int oh = s / 112, ow = s % 112;
    float a = bias[co];
    int kh0 = (oh + 1) & 1, kw0 = (ow + 1) & 1;
    #pragma unroll
    for (int dh = 0; dh < 2; ++dh) {
        int kh = kh0 + 2 * dh;
        int ih = (oh + 1 - kh) >> 1;
        if ((unsigned)ih >= 56u) continue;
        #pragma unroll
        for (int dw = 0; dw < 2; ++dw) {
            int kw = kw0 + 2 * dw;
            int iw = (ow + 1 - kw) >> 1;
            if ((unsigned)iw >= 56u) continue;
            const float* dp = d + ih * 56 + iw;
            const float* wp = w + co * 16 + kh * 4 + kw;   // [ci][64co][4][4]
            float t = 0.f;
            for (int ci = 0; ci < 128; ++ci) t += dp[ci * 3136] * wp[ci * 1024];
            a += t;
        }
    }
    d2[co * 12544 + s] = fmaxf(a, 0.f);
}

// ---------------- kernel 8: R = convT(d2, w_dt2) [224,224], once ----------------
__global__ __launch_bounds__(256) void k_R(const float* __restrict__ d2,
                                           const float* __restrict__ w,
                                           const float* __restrict__ bias,
                                           float* __restrict__ R) {
    int s = blockIdx.x * 256 + threadIdx.x;   // 50176
    int oh = s / 224, ow = s % 224;
    float a = bias[0];
    int kh0 = (oh + 1) & 1, kw0 = (ow + 1) & 1;
    #pragma unroll
    for (int dh = 0; dh < 2; ++dh) {
        int kh = kh0 + 2 * dh;
        int ih = (oh + 1 - kh) >> 1;
        if ((unsigned)ih >= 112u) continue;
        #pragma unroll
        for (int dw = 0; dw < 2; ++dw) {
            int kw = kw0 + 2 * dw;
            int iw = (ow + 1 - kw) >> 1;
            if ((unsigned)iw >= 112u) continue;
            const float* dp = d2 + ih * 112 + iw;
            const float* wp = w + kh * 4 + kw;  // [64ci][1][4][4]
            float t = 0.f;
            for (int ci = 0; ci < 64; ++ci) t += dp[ci * 12544] * wp[ci * 16];
            a += t;
        }
    }
    R[s] = a;
}

// ---------------- kernel 9: replicate R into out, rec-loss partials ----------------
__global__ __launch_bounds__(256) void k_out(const float* __restrict__ R,
                                             const float* __restrict__ x,
                                             float* __restrict__ out,
                                             float* __restrict__ rec_part) {
    int idx = blockIdx.x * 256 + threadIdx.x;  // 1,605,632
    int s = idx % 50176;
    float r = R[s];
    out[idx] = r;
    float df = r - x[idx];
    float v = df * df;
    __shared__ float red[4];
    #pragma unroll
    for (int off = 32; off > 0; off >>= 1) v += __shfl_down(v, off);
    int wid = threadIdx.x >> 6, lane = threadIdx.x & 63;
    if (lane == 0) red[wid] = v;
    __syncthreads();
    if (threadIdx.x == 0) rec_part[blockIdx.x] = red[0] + red[1] + red[2] + red[3];
}

// ---------------- kernel 10: deterministic finalize ----------------
__global__ __launch_bounds__(256) void k_fin(const float* __restrict__ vq_part,
                                             const float* __restrict__ rec_part,
                                             float* __restrict__ out, int loss_base) {
    __shared__ float sv[256], sr[256];
    float a = 0.f, b2 = 0.f;
    for (int i = threadIdx.x; i < 14336; i += 256) a  += vq_part[i];
    for (int i = threadIdx.x; i < 6272;  i += 256) b2 += rec_part[i];
    sv[threadIdx.x] = a; sr[threadIdx.x] = b2;
    __syncthreads();
    for (int off = 128; off > 0; off >>= 1) {
        if (threadIdx.x < off) { sv[threadIdx.x] += sv[threadIdx.x + off]; sr[threadIdx.x] += sr[threadIdx.x + off]; }
        __syncthreads();
    }
    if (threadIdx.x == 0) {
        float vq  = 2.f * sv[0] / 12845056.f;   // 2*mean((z_q - z_e)^2), both losses equal
        float rec = sr[0] / 1605632.f;
        out[loss_base + 0] = rec + vq;
        out[loss_base + 1] = rec;
        out[loss_base + 2] = vq;
    }
}

extern "C" void kernel_launch(void* const* d_in, const int* in_sizes, int n_in,
                              void* d_out, int out_size, void* d_ws, size_t ws_size,
                              hipStream_t stream) {
    const float* x     = (const float*)d_in[0];
    const float* w_e1  = (const float*)d_in[1];
    const float* b_e1  = (const float*)d_in[2];
    const float* w_e2  = (const float*)d_in[3];
    const float* b_e2  = (const float*)d_in[4];
    const float* w_e3  = (const float*)d_in[5];
    const float* b_e3  = (const float*)d_in[6];
    const float* emb   = (const float*)d_in[7];
    const float* w_d1  = (const float*)d_in[8];
    const float* b_d1  = (const float*)d_in[9];
    const float* w_dt1 = (const float*)d_in[10];
    const float* b_dt1 = (const float*)d_in[11];
    const float* w_dt2 = (const float*)d_in[12];
    const float* b_dt2 = (const float*)d_in[13];
    float* out = (float*)d_out;
    float* ws  = (float*)d_ws;

    // ws layout (float offsets)
    float* c        = ws + 16;        // 128
    float* S        = ws + 160;       // 1152
    float* dbuf     = ws + 2048;      // 401408
    float* d2       = ws + 403456;    // 802816
    float* R        = ws + 1206272;   // 50176
    float* vq_part  = ws + 1256448;   // 14336
    float* rec_part = ws + 1270784;   // 6272
    bf16*  h1       = (bf16*)(ws + 1310720);   // 25,690,112 bf16
    bf16*  h2       = (bf16*)(ws + 14155776);  // 12,845,056 bf16
    // total: 20,578,304 floats = 82.3 MB

    k_codebook<<<1, 512, 0, stream>>>(emb, c);
    k_conv1<<<dim3(49, 64, 32), 256, 0, stream>>>(x, w_e1, b_e1, h1);
    k_conv2<<<dim3(56, 8, 32), 64, 0, stream>>>(h1, w_e2, b_e2, h2);
    k_conv3_vq<<<dim3(56, 8, 32), 64, 0, stream>>>(h2, w_e3, b_e3, c, vq_part);
    k_S<<<9, 128, 0, stream>>>(w_d1, c, S);
    k_d<<<1568, 256, 0, stream>>>(S, b_d1, dbuf);
    k_d2<<<dim3(49, 64), 256, 0, stream>>>(dbuf, w_dt1, b_dt1, d2);
    k_R<<<196, 256, 0, stream>>>(d2, w_dt2, b_dt2, R);
    k_out<<<6272, 256, 0, stream>>>(R, x, out, rec_part);
    k_fin<<<1, 256, 0, stream>>>(vq_part, rec_part, out, out_size - 3);
}

// Round 2
// 597.344 us; speedup vs baseline: 7.6661x; 7.6661x over previous
//
#include <hip/hip_runtime.h>
#include <hip/hip_bf16.h>

using bf16 = __hip_bfloat16;
using short8 = __attribute__((ext_vector_type(8))) short;
using f32x16 = __attribute__((ext_vector_type(16))) float;

__device__ __forceinline__ ushort f2us(float v) {
    bf16 h = __float2bfloat16(v);
    return *reinterpret_cast<ushort*>(&h);
}

#define MFMA32(a, b, c) __builtin_amdgcn_mfma_f32_32x32x16_bf16((a), (b), (c), 0, 0, 0)

// ---------------- kernel 1: codebook argmin + extract c ----------------
__global__ void k_codebook(const float* __restrict__ emb, float* __restrict__ c) {
    __shared__ float sval[512];
    __shared__ int   sidx[512];
    int k = threadIdx.x;
    float s = 0.f;
    const float* e = emb + k * 128;
    for (int d = 0; d < 128; ++d) { float v = e[d]; s += v * v; }
    sval[k] = s; sidx[k] = k;
    __syncthreads();
    for (int off = 256; off > 0; off >>= 1) {
        if (k < off) {
            float v2 = sval[k + off]; int i2 = sidx[k + off];
            if (v2 < sval[k] || (v2 == sval[k] && i2 < sidx[k])) { sval[k] = v2; sidx[k] = i2; }
        }
        __syncthreads();
    }
    int kmin = sidx[0];
    if (k < 128) c[k] = emb[kmin * 128 + k];
}

// ---------------- weight prepack: w_e2 -> Wb2[tap16][co128][ci64] bf16,
//                  w_e3 -> Wb3[tap9][co128][ci128] bf16 ----------------
__global__ __launch_bounds__(256) void k_prepack(const float* __restrict__ w_e2,
                                                 const float* __restrict__ w_e3,
                                                 ushort* __restrict__ Wb2,
                                                 ushort* __restrict__ Wb3) {
    int i = blockIdx.x * 256 + threadIdx.x;
    const int n2 = 16 * 128 * 64;   // 131072
    const int n3 = 9 * 128 * 128;   // 147456
    if (i < n2) {
        int tap = i >> 13; int rem = i & 8191; int co = rem >> 6; int ci = rem & 63;
        int kh = tap >> 2, kw = tap & 3;
        Wb2[i] = f2us(w_e2[((co * 64 + ci) * 4 + kh) * 4 + kw]);
    } else if (i < n2 + n3) {
        int j = i - n2;
        int tap = j / 16384; int rem = j & 16383; int co = rem >> 7; int ci = rem & 127;
        int kh = tap / 3, kw = tap % 3;
        Wb3[j] = f2us(w_e3[((co * 128 + ci) * 3 + kh) * 3 + kw]);
    }
}

// ---------------- conv1 (1->64, k4 s2 p1) + relu -> h1q quadrant layout ----------------
// h1q[b][pq=(ih&1)*2+(iw&1)][ci][ih>>1][iw>>1], each quadrant 56x56
__global__ __launch_bounds__(256) void k_conv1(const float* __restrict__ x,
                                               const float* __restrict__ w,
                                               const float* __restrict__ bias,
                                               ushort* __restrict__ h1q) {
    int s  = blockIdx.x * 256 + threadIdx.x;   // 0..12543 (112*112)
    int co = blockIdx.y;                        // 64
    int b  = blockIdx.z;                        // 32
    int oh = s / 112, ow = s % 112;
    float acc = bias[co];
    const float* xb = x + b * 224 * 224;
    const float* wc = w + co * 16;
    #pragma unroll
    for (int kh = 0; kh < 4; ++kh) {
        int ih = 2 * oh - 1 + kh;
        if ((unsigned)ih < 224u) {
            #pragma unroll
            for (int kw = 0; kw < 4; ++kw) {
                int iw = 2 * ow - 1 + kw;
                if ((unsigned)iw < 224u) acc += xb[ih * 224 + iw] * wc[kh * 4 + kw];
            }
        }
    }
    acc = fmaxf(acc, 0.f);
    int pq = (oh & 1) * 2 + (ow & 1);
    h1q[((size_t)(b * 4 + pq) * 64 + co) * 3136 + (oh >> 1) * 56 + (ow >> 1)] = f2us(acc);
}

// ---------------- conv2 MFMA (64->128, k4 s2 p1) + relu -> h2 bf16 ----------------
// block: (oh, b), 256 thr = 4 waves (2M x 2N). Tap-GEMM over parity quadrants.
__global__ __launch_bounds__(256) void k_conv2_mfma(const ushort* __restrict__ h1q,
                                                    const ushort* __restrict__ Wb2,
                                                    const float* __restrict__ bias,
                                                    ushort* __restrict__ h2) {
    // lds[pw][w(58)][ci(72 padded)] for current kh slab
    __shared__ __align__(16) ushort lds[2 * 58 * 72];   // 16704 B
    int oh = blockIdx.x, b = blockIdx.y;
    int tid = threadIdx.x, lane = tid & 63, wv = tid >> 6;
    int lrow = lane & 31, khalf = lane >> 5;
    int m0 = (wv & 1) * 64;
    int n0 = (wv >> 1) * 24;

    // zero border columns w=0 and w=57 (never staged, stay zero across kh slabs)
    {
        int pw = tid >> 7, wsel = (tid >> 6) & 1, ci = tid & 63;
        lds[(pw * 58 + wsel * 57) * 72 + ci] = 0;
    }

    const f32x16 vz = {0,0,0,0,0,0,0,0,0,0,0,0,0,0,0,0};
    f32x16 acc0 = vz, acc1 = vz;

    for (int kh = 0; kh < 4; ++kh) {
        int ph = (kh == 0 || kh == 2) ? 1 : 0;
        int r  = oh + ((kh == 0) ? -1 : (kh == 3) ? 1 : 0);
        __syncthreads();   // previous compute done reading lds
        if ((unsigned)r < 56u) {
            // stage 128 rows (pw,ci), transposed into [w][ci]
            for (int pass = 0; pass < 16; ++pass) {
                int rid = pass * 8 + (tid >> 5);
                int sub = tid & 31;
                int pw = rid >> 6, ci = rid & 63;
                if (sub < 28) {
                    const uint* src = (const uint*)(h1q +
                        ((size_t)((b * 4 + ph * 2 + pw) * 64 + ci)) * 3136 + r * 56);
                    uint pv = src[sub];
                    int base = (pw * 58 + 2 * sub + 1) * 72 + ci;
                    lds[base]      = (ushort)(pv & 0xffffu);
                    lds[base + 72] = (ushort)(pv >> 16);
                }
            }
        } else {
            // out-of-range row -> zero slab (padding semantics)
            float4 z4 = {0.f, 0.f, 0.f, 0.f};
            for (int i = tid; i < 1044; i += 256) ((float4*)lds)[i] = z4;
        }
        __syncthreads();
        #pragma unroll
        for (int kw = 0; kw < 4; ++kw) {
            int tap  = kh * 4 + kw;
            int pw   = (kw & 1) ? 0 : 1;
            int wofs = (kw == 0) ? 0 : (kw == 3) ? 2 : 1;   // dw+1
            const ushort* wa = Wb2 + ((size_t)tap * 128 + m0 + lrow) * 64 + khalf * 8;
            const ushort* bp = &lds[(pw * 58 + n0 + lrow + wofs) * 72 + khalf * 8];
            #pragma unroll
            for (int ks = 0; ks < 4; ++ks) {
                short8 bv = *(const short8*)(bp + ks * 16);
                short8 a0 = *(const short8*)(wa + ks * 16);
                short8 a1 = *(const short8*)(wa + 32 * 64 + ks * 16);
                acc0 = MFMA32(a0, bv, acc0);
                acc1 = MFMA32(a1, bv, acc1);
            }
        }
    }
    // store: D col=lane&31 -> ow, row=(reg&3)+8*(reg>>2)+4*(lane>>5)
    int ow = n0 + lrow;
    bool wr = (wv >> 1) == 0 || lrow >= 8;   // dedupe overlap cols 24..31
    if (wr) {
        #pragma unroll
        for (int mf = 0; mf < 2; ++mf) {
            #pragma unroll
            for (int reg = 0; reg < 16; ++reg) {
                int co = m0 + mf * 32 + (reg & 3) + 8 * (reg >> 2) + 4 * khalf;
                float v = (mf ? acc1[reg] : acc0[reg]) + bias[co];
                v = fmaxf(v, 0.f);
                h2[((size_t)(b * 128 + co) * 56 + oh) * 56 + ow] = f2us(v);
            }
        }
    }
}

// ---------------- conv3 MFMA (128->128, k3 s1 p1), fused vq-loss ----------------
__global__ __launch_bounds__(256) void k_conv3_mfma(const ushort* __restrict__ h2,
                                                    const ushort* __restrict__ Wb3,
                                                    const float* __restrict__ bias,
                                                    const float* __restrict__ c,
                                                    float* __restrict__ vq_part) {
    __shared__ __align__(16) ushort lds[58 * 136];   // 15776 B, [w][ci(136 padded)]
    __shared__ float red[4];
    int oh = blockIdx.x, b = blockIdx.y;
    int tid = threadIdx.x, lane = tid & 63, wv = tid >> 6;
    int lrow = lane & 31, khalf = lane >> 5;
    int m0 = (wv & 1) * 64;
    int n0 = (wv >> 1) * 24;

    {   // zero border columns w=0 / w=57
        int wsel = tid >> 7, ci = tid & 127;
        lds[(wsel * 57) * 136 + ci] = 0;
    }

    const f32x16 vz = {0,0,0,0,0,0,0,0,0,0,0,0,0,0,0,0};
    f32x16 acc0 = vz, acc1 = vz;

    for (int kh = 0; kh < 3; ++kh) {
        int r = oh - 1 + kh;
        __syncthreads();
        if ((unsigned)r < 56u) {
            for (int pass = 0; pass < 16; ++pass) {
                int ci  = pass * 8 + (tid >> 5);   // 0..127
                int sub = tid & 31;
                if (sub < 28) {
                    const uint* src = (const uint*)(h2 + ((size_t)(b * 128 + ci) * 56 + r) * 56);
                    uint pv = src[sub];
                    int base = (2 * sub + 1) * 136 + ci;
                    lds[base]       = (ushort)(pv & 0xffffu);
                    lds[base + 136] = (ushort)(pv >> 16);
                }
            }
        } else {
            float4 z4 = {0.f, 0.f, 0.f, 0.f};
            for (int i = tid; i < 986; i += 256) ((float4*)lds)[i] = z4;
        }
        __syncthreads();
        #pragma unroll
        for (int kw = 0; kw < 3; ++kw) {
            int tap = kh * 3 + kw;
            const ushort* wa = Wb3 + ((size_t)tap * 128 + m0 + lrow) * 128 + khalf * 8;
            const ushort* bp = &lds[(n0 + lrow + kw) * 136 + khalf * 8];
            #pragma unroll
            for (int ks = 0; ks < 8; ++ks) {
                short8 bv = *(const short8*)(bp + ks * 16);
                short8 a0 = *(const short8*)(wa + ks * 16);
                short8 a1 = *(const short8*)(wa + 32 * 128 + ks * 16);
                acc0 = MFMA32(a0, bv, acc0);
                acc1 = MFMA32(a1, bv, acc1);
            }
        }
    }
    // fused vq loss: sum (c[co] - z_e)^2 over owned (unique) columns
    float ls = 0.f;
    bool wr = (wv >> 1) == 0 || lrow >= 8;
    if (wr) {
        #pragma unroll
        for (int mf = 0; mf < 2; ++mf) {
            #pragma unroll
            for (int reg = 0; reg < 16; ++reg) {
                int co = m0 + mf * 32 + (reg & 3) + 8 * (reg >> 2) + 4 * khalf;
                float z = (mf ? acc1[reg] : acc0[reg]) + bias[co];
                float d = c[co] - z;
                ls += d * d;
            }
        }
    }
    #pragma unroll
    for (int off = 32; off > 0; off >>= 1) ls += __shfl_down(ls, off);
    if (lane == 0) red[wv] = ls;
    __syncthreads();
    if (tid == 0) vq_part[b * 56 + oh] = red[0] + red[1] + red[2] + red[3];
}

// ---------------- decoder (constant z_q path, computed once) ----------------
__global__ void k_S(const float* __restrict__ w_d1, const float* __restrict__ c,
                    float* __restrict__ S) {
    int khw = blockIdx.x;   // 0..8
    int co  = threadIdx.x;  // 128
    float s = 0.f;
    for (int ci = 0; ci < 128; ++ci) s += w_d1[(co * 128 + ci) * 9 + khw] * c[ci];
    S[co * 9 + khw] = s;
}

__global__ __launch_bounds__(256) void k_d(const float* __restrict__ S,
                                           const float* __restrict__ bias,
                                           float* __restrict__ d) {
    int idx = blockIdx.x * 256 + threadIdx.x;  // < 401408
    int co = idx / 3136; int s = idx % 3136; int h = s / 56, w0 = s % 56;
    float a = bias[co];
    const float* Sc = S + co * 9;
    #pragma unroll
    for (int kh = 0; kh < 3; ++kh) {
        int ih = h - 1 + kh;
        if ((unsigned)ih >= 56u) continue;
        #pragma unroll
        for (int kw = 0; kw < 3; ++kw) {
            int iw = w0 - 1 + kw;
            if ((unsigned)iw < 56u) a += Sc[kh * 3 + kw];
        }
    }
    d[idx] = a;
}

__global__ __launch_bounds__(256) void k_d2(const float* __restrict__ d,
                                            const float* __restrict__ w,
                                            const float* __restrict__ bias,
                                            float* __restrict__ d2) {
    int s  = blockIdx.x * 256 + threadIdx.x;  // 0..12543
    int co = blockIdx.y;                      // 64
    int oh = s / 112, ow = s % 112;
    float a = bias[co];
    int kh0 = (oh + 1) & 1, kw0 = (ow + 1) & 1;
    #pragma unroll
    for (int dh = 0; dh < 2; ++dh) {
        int kh = kh0 + 2 * dh;
        int ih = (oh + 1 - kh) >> 1;
        if ((unsigned)ih >= 56u) continue;
        #pragma unroll
        for (int dw = 0; dw < 2; ++dw) {
            int kw = kw0 + 2 * dw;
            int iw = (ow + 1 - kw) >> 1;
            if ((unsigned)iw >= 56u) continue;
            const float* dp = d + ih * 56 + iw;
            const float* wp = w + co * 16 + kh * 4 + kw;   // [ci][64co][4][4]
            float t = 0.f;
            for (int ci = 0; ci < 128; ++ci) t += dp[ci * 3136] * wp[ci * 1024];
            a += t;
        }
    }
    d2[co * 12544 + s] = fmaxf(a, 0.f);
}

__global__ __launch_bounds__(256) void k_R(const float* __restrict__ d2,
                                           const float* __restrict__ w,
                                           const float* __restrict__ bias,
                                           float* __restrict__ R) {
    int s = blockIdx.x * 256 + threadIdx.x;   // 50176
    int oh = s / 224, ow = s % 224;
    float a = bias[0];
    int kh0 = (oh + 1) & 1, kw0 = (ow + 1) & 1;
    #pragma unroll
    for (int dh = 0; dh < 2; ++dh) {
        int kh = kh0 + 2 * dh;
        int ih = (oh + 1 - kh) >> 1;
        if ((unsigned)ih >= 112u) continue;
        #pragma unroll
        for (int dw = 0; dw < 2; ++dw) {
            int kw = kw0 + 2 * dw;
            int iw = (ow + 1 - kw) >> 1;
            if ((unsigned)iw >= 112u) continue;
            const float* dp = d2 + ih * 112 + iw;
            const float* wp = w + kh * 4 + kw;  // [64ci][1][4][4]
            float t = 0.f;
            for (int ci = 0; ci < 64; ++ci) t += dp[ci * 12544] * wp[ci * 16];
            a += t;
        }
    }
    R[s] = a;
}

__global__ __launch_bounds__(256) void k_out(const float* __restrict__ R,
                                             const float* __restrict__ x,
                                             float* __restrict__ out,
                                             float* __restrict__ rec_part) {
    int idx = blockIdx.x * 256 + threadIdx.x;  // 1,605,632
    int s = idx % 50176;
    float r = R[s];
    out[idx] = r;
    float df = r - x[idx];
    float v = df * df;
    __shared__ float red[4];
    #pragma unroll
    for (int off = 32; off > 0; off >>= 1) v += __shfl_down(v, off);
    int wid = threadIdx.x >> 6, lane = threadIdx.x & 63;
    if (lane == 0) red[wid] = v;
    __syncthreads();
    if (threadIdx.x == 0) rec_part[blockIdx.x] = red[0] + red[1] + red[2] + red[3];
}

__global__ __launch_bounds__(256) void k_fin(const float* __restrict__ vq_part,
                                             const float* __restrict__ rec_part,
                                             float* __restrict__ out, int loss_base) {
    __shared__ float sv[256], sr[256];
    float a = 0.f, b2 = 0.f;
    for (int i = threadIdx.x; i < 1792; i += 256) a  += vq_part[i];
    for (int i = threadIdx.x; i < 6272; i += 256) b2 += rec_part[i];
    sv[threadIdx.x] = a; sr[threadIdx.x] = b2;
    __syncthreads();
    for (int off = 128; off > 0; off >>= 1) {
        if (threadIdx.x < off) { sv[threadIdx.x] += sv[threadIdx.x + off]; sr[threadIdx.x] += sr[threadIdx.x + off]; }
        __syncthreads();
    }
    if (threadIdx.x == 0) {
        float vq  = 2.f * sv[0] / 12845056.f;   // codebook + commitment (equal)
        float rec = sr[0] / 1605632.f;
        out[loss_base + 0] = rec + vq;
        out[loss_base + 1] = rec;
        out[loss_base + 2] = vq;
    }
}

extern "C" void kernel_launch(void* const* d_in, const int* in_sizes, int n_in,
                              void* d_out, int out_size, void* d_ws, size_t ws_size,
                              hipStream_t stream) {
    const float* x     = (const float*)d_in[0];
    const float* w_e1  = (const float*)d_in[1];
    const float* b_e1  = (const float*)d_in[2];
    const float* w_e2  = (const float*)d_in[3];
    const float* b_e2  = (const float*)d_in[4];
    const float* w_e3  = (const float*)d_in[5];
    const float* b_e3  = (const float*)d_in[6];
    const float* emb   = (const float*)d_in[7];
    const float* w_d1  = (const float*)d_in[8];
    const float* b_d1  = (const float*)d_in[9];
    const float* w_dt1 = (const float*)d_in[10];
    const float* b_dt1 = (const float*)d_in[11];
    const float* w_dt2 = (const float*)d_in[12];
    const float* b_dt2 = (const float*)d_in[13];
    float* out = (float*)d_out;
    float* ws  = (float*)d_ws;

    // ws layout (float offsets) — total 20,578,304 floats = 82.3 MB (same as r0)
    float* c        = ws + 16;        // 128
    float* S        = ws + 160;       // 1152
    // Wb2/Wb3 overlay dbuf's region: dead before k_S/k_d write dbuf (stream order)
    ushort* Wb2     = (ushort*)(ws + 2048);    // 131072 us (65536 f)
    ushort* Wb3     = (ushort*)(ws + 67584);   // 147456 us (73728 f) -> ends 141312
    float* dbuf     = ws + 2048;      // 401408
    float* d2       = ws + 403456;    // 802816
    float* R        = ws + 1206272;   // 50176
    float* vq_part  = ws + 1256448;   // 1792
    float* rec_part = ws + 1270784;   // 6272
    ushort* h1q     = (ushort*)(ws + 1310720);   // 25,690,112 us
    ushort* h2      = (ushort*)(ws + 14155776);  // 12,845,056 us

    k_codebook<<<1, 512, 0, stream>>>(emb, c);
    k_prepack<<<1088, 256, 0, stream>>>(w_e2, w_e3, Wb2, Wb3);
    k_conv1<<<dim3(49, 64, 32), 256, 0, stream>>>(x, w_e1, b_e1, h1q);
    k_conv2_mfma<<<dim3(56, 32), 256, 0, stream>>>(h1q, Wb2, b_e2, h2);
    k_conv3_mfma<<<dim3(56, 32), 256, 0, stream>>>(h2, Wb3, b_e3, c, vq_part);
    k_S<<<9, 128, 0, stream>>>(w_d1, c, S);
    k_d<<<1568, 256, 0, stream>>>(S, b_d1, dbuf);
    k_d2<<<dim3(49, 64), 256, 0, stream>>>(dbuf, w_dt1, b_dt1, d2);
    k_R<<<196, 256, 0, stream>>>(d2, w_dt2, b_dt2, R);
    k_out<<<6272, 256, 0, stream>>>(R, x, out, rec_part);
    k_fin<<<1, 256, 0, stream>>>(vq_part, rec_part, out, out_size - 3);
}

// Round 3
// 344.893 us; speedup vs baseline: 13.2775x; 1.7320x over previous
//
#include <hip/hip_runtime.h>
#include <hip/hip_bf16.h>

using bf16 = __hip_bfloat16;
using short8 = __attribute__((ext_vector_type(8))) short;
using f32x16 = __attribute__((ext_vector_type(16))) float;

__device__ __forceinline__ ushort f2us(float v) {
    bf16 h = __float2bfloat16(v);
    return *reinterpret_cast<ushort*>(&h);
}

#define MFMA32(a, b, c) __builtin_amdgcn_mfma_f32_32x32x16_bf16((a), (b), (c), 0, 0, 0)

// class of a row index in the 112-domain (d2 rows / convT2 inputs)
__device__ __forceinline__ int cls8(int i) {
    if (i == 0) return 0;
    if (i == 1) return 1;
    if (i == 2) return 2;
    if (i == 109) return 5;
    if (i == 110) return 6;
    if (i == 111) return 7;
    return (i & 1) ? 4 : 3;
}

// ---------------- kernel 1: codebook argmin + extract c ----------------
__global__ void k_codebook(const float* __restrict__ emb, float* __restrict__ c) {
    __shared__ float sval[512];
    __shared__ int   sidx[512];
    int k = threadIdx.x;
    float s = 0.f;
    const float4* e4 = (const float4*)(emb + k * 128);
    #pragma unroll
    for (int d = 0; d < 32; ++d) {
        float4 v = e4[d];
        s += v.x * v.x + v.y * v.y + v.z * v.z + v.w * v.w;
    }
    sval[k] = s; sidx[k] = k;
    __syncthreads();
    for (int off = 256; off > 0; off >>= 1) {
        if (k < off) {
            float v2 = sval[k + off]; int i2 = sidx[k + off];
            if (v2 < sval[k] || (v2 == sval[k] && i2 < sidx[k])) { sval[k] = v2; sidx[k] = i2; }
        }
        __syncthreads();
    }
    int kmin = sidx[0];
    if (k < 128) c[k] = emb[kmin * 128 + k];
}

// ---------------- weight prepack: w_e2 -> Wb2[tap16][co128][ci64] bf16,
//                  w_e3 -> Wb3[tap9][co128][ci128] bf16 ----------------
__global__ __launch_bounds__(256) void k_prepack(const float* __restrict__ w_e2,
                                                 const float* __restrict__ w_e3,
                                                 ushort* __restrict__ Wb2,
                                                 ushort* __restrict__ Wb3) {
    int i = blockIdx.x * 256 + threadIdx.x;
    const int n2 = 16 * 128 * 64;   // 131072
    const int n3 = 9 * 128 * 128;   // 147456
    if (i < n2) {
        int tap = i >> 13; int rem = i & 8191; int co = rem >> 6; int ci = rem & 63;
        int kh = tap >> 2, kw = tap & 3;
        Wb2[i] = f2us(w_e2[((co * 64 + ci) * 4 + kh) * 4 + kw]);
    } else if (i < n2 + n3) {
        int j = i - n2;
        int tap = j / 16384; int rem = j & 16383; int co = rem >> 7; int ci = rem & 127;
        int kh = tap / 3, kw = tap % 3;
        Wb3[j] = f2us(w_e3[((co * 128 + ci) * 3 + kh) * 3 + kw]);
    }
}

// ---------------- conv1 (1->64, k4 s2 p1) + relu -> h1q quadrant layout ----------------
// h1q[b][pq=(oh&1)*2+(ow&1)][ci][oh>>1][ow>>1]. Thread: 2 positions (ow pair) x 32 co.
__global__ __launch_bounds__(256) void k_conv1(const float* __restrict__ x,
                                               const float* __restrict__ w,
                                               const float* __restrict__ bias,
                                               ushort* __restrict__ h1q) {
    __shared__ float wl[512];
    __shared__ float bl[32];
    int tid = threadIdx.x;
    int co0 = blockIdx.y * 32;
    wl[tid]       = w[co0 * 16 + tid];
    wl[tid + 256] = w[co0 * 16 + 256 + tid];
    if (tid < 32) bl[tid] = bias[co0 + tid];
    __syncthreads();
    int s = blockIdx.x * 256 + tid;
    if (s >= 6272) return;           // 112 oh * 56 ow-pairs
    int oh = s / 56, owp = s % 56;
    int b = blockIdx.z;
    const float* xb = x + (size_t)b * 50176;
    float xv[4][6];
    #pragma unroll
    for (int kh = 0; kh < 4; ++kh) {
        int ih = 2 * oh - 1 + kh;
        bool rok = (unsigned)ih < 224u;
        const float* xr = xb + ih * 224;
        #pragma unroll
        for (int j = 0; j < 6; ++j) {
            int iw = 4 * owp - 1 + j;
            xv[kh][j] = (rok && (unsigned)iw < 224u) ? xr[iw] : 0.f;
        }
    }
    int pq0 = (oh & 1) * 2;           // ow=2*owp is even; +1 plane for odd
    size_t base = ((size_t)(b * 4 + pq0) * 64 + co0) * 3136 + (oh >> 1) * 56 + owp;
    for (int co = 0; co < 32; ++co) {
        float a0 = bl[co], a1 = a0;
        const float* wc = &wl[co * 16];
        #pragma unroll
        for (int kh = 0; kh < 4; ++kh) {
            #pragma unroll
            for (int kw = 0; kw < 4; ++kw) {
                float wv = wc[kh * 4 + kw];
                a0 += xv[kh][kw] * wv;       // ow = 2*owp
                a1 += xv[kh][kw + 2] * wv;   // ow = 2*owp+1
            }
        }
        h1q[base + (size_t)co * 3136]        = f2us(fmaxf(a0, 0.f));
        h1q[base + (size_t)(64 + co) * 3136] = f2us(fmaxf(a1, 0.f));
    }
}

// ---------------- conv2 MFMA (64->128, k4 s2 p1) + relu -> h2 bf16 ----------------
__global__ __launch_bounds__(256) void k_conv2_mfma(const ushort* __restrict__ h1q,
                                                    const ushort* __restrict__ Wb2,
                                                    const float* __restrict__ bias,
                                                    ushort* __restrict__ h2) {
    __shared__ __align__(16) ushort lds[2 * 58 * 72];   // [pw][w(58)][ci(72 pad)]
    int oh = blockIdx.x, b = blockIdx.y;
    int tid = threadIdx.x, lane = tid & 63, wv = tid >> 6;
    int lrow = lane & 31, khalf = lane >> 5;
    int m0 = (wv & 1) * 64;
    int n0 = (wv >> 1) * 24;

    {   // zero border columns w=0 and w=57
        int pw = tid >> 7, wsel = (tid >> 6) & 1, ci = tid & 63;
        lds[(pw * 58 + wsel * 57) * 72 + ci] = 0;
    }

    const f32x16 vz = {0,0,0,0,0,0,0,0,0,0,0,0,0,0,0,0};
    f32x16 acc0 = vz, acc1 = vz;

    for (int kh = 0; kh < 4; ++kh) {
        int ph = (kh == 0 || kh == 2) ? 1 : 0;
        int r  = oh + ((kh == 0) ? -1 : (kh == 3) ? 1 : 0);
        __syncthreads();
        if ((unsigned)r < 56u) {
            for (int pass = 0; pass < 16; ++pass) {
                int rid = pass * 8 + (tid >> 5);
                int sub = tid & 31;
                int pw = rid >> 6, ci = rid & 63;
                if (sub < 28) {
                    const uint* src = (const uint*)(h1q +
                        ((size_t)((b * 4 + ph * 2 + pw) * 64 + ci)) * 3136 + r * 56);
                    uint pv = src[sub];
                    int base = (pw * 58 + 2 * sub + 1) * 72 + ci;
                    lds[base]      = (ushort)(pv & 0xffffu);
                    lds[base + 72] = (ushort)(pv >> 16);
                }
            }
        } else {
            float4 z4 = {0.f, 0.f, 0.f, 0.f};
            for (int i = tid; i < 1044; i += 256) ((float4*)lds)[i] = z4;
        }
        __syncthreads();
        #pragma unroll
        for (int kw = 0; kw < 4; ++kw) {
            int tap  = kh * 4 + kw;
            int pw   = (kw & 1) ? 0 : 1;
            int wofs = (kw == 0) ? 0 : (kw == 3) ? 2 : 1;
            const ushort* wa = Wb2 + ((size_t)tap * 128 + m0 + lrow) * 64 + khalf * 8;
            const ushort* bp = &lds[(pw * 58 + n0 + lrow + wofs) * 72 + khalf * 8];
            #pragma unroll
            for (int ks = 0; ks < 4; ++ks) {
                short8 bv = *(const short8*)(bp + ks * 16);
                short8 a0 = *(const short8*)(wa + ks * 16);
                short8 a1 = *(const short8*)(wa + 32 * 64 + ks * 16);
                acc0 = MFMA32(a0, bv, acc0);
                acc1 = MFMA32(a1, bv, acc1);
            }
        }
    }
    int ow = n0 + lrow;
    bool wr = (wv >> 1) == 0 || lrow >= 8;
    if (wr) {
        #pragma unroll
        for (int mf = 0; mf < 2; ++mf) {
            #pragma unroll
            for (int reg = 0; reg < 16; ++reg) {
                int co = m0 + mf * 32 + (reg & 3) + 8 * (reg >> 2) + 4 * khalf;
                float v = (mf ? acc1[reg] : acc0[reg]) + bias[co];
                v = fmaxf(v, 0.f);
                h2[((size_t)(b * 128 + co) * 56 + oh) * 56 + ow] = f2us(v);
            }
        }
    }
}

// ---------------- conv3 MFMA (128->128, k3 s1 p1), fused vq-loss ----------------
__global__ __launch_bounds__(256) void k_conv3_mfma(const ushort* __restrict__ h2,
                                                    const ushort* __restrict__ Wb3,
                                                    const float* __restrict__ bias,
                                                    const float* __restrict__ c,
                                                    float* __restrict__ vq_part) {
    __shared__ __align__(16) ushort lds[58 * 136];
    __shared__ float red[4];
    int oh = blockIdx.x, b = blockIdx.y;
    int tid = threadIdx.x, lane = tid & 63, wv = tid >> 6;
    int lrow = lane & 31, khalf = lane >> 5;
    int m0 = (wv & 1) * 64;
    int n0 = (wv >> 1) * 24;

    {
        int wsel = tid >> 7, ci = tid & 127;
        lds[(wsel * 57) * 136 + ci] = 0;
    }

    const f32x16 vz = {0,0,0,0,0,0,0,0,0,0,0,0,0,0,0,0};
    f32x16 acc0 = vz, acc1 = vz;

    for (int kh = 0; kh < 3; ++kh) {
        int r = oh - 1 + kh;
        __syncthreads();
        if ((unsigned)r < 56u) {
            for (int pass = 0; pass < 16; ++pass) {
                int ci  = pass * 8 + (tid >> 5);
                int sub = tid & 31;
                if (sub < 28) {
                    const uint* src = (const uint*)(h2 + ((size_t)(b * 128 + ci) * 56 + r) * 56);
                    uint pv = src[sub];
                    int base = (2 * sub + 1) * 136 + ci;
                    lds[base]       = (ushort)(pv & 0xffffu);
                    lds[base + 136] = (ushort)(pv >> 16);
                }
            }
        } else {
            float4 z4 = {0.f, 0.f, 0.f, 0.f};
            for (int i = tid; i < 986; i += 256) ((float4*)lds)[i] = z4;
        }
        __syncthreads();
        #pragma unroll
        for (int kw = 0; kw < 3; ++kw) {
            int tap = kh * 3 + kw;
            const ushort* wa = Wb3 + ((size_t)tap * 128 + m0 + lrow) * 128 + khalf * 8;
            const ushort* bp = &lds[(n0 + lrow + kw) * 136 + khalf * 8];
            #pragma unroll
            for (int ks = 0; ks < 8; ++ks) {
                short8 bv = *(const short8*)(bp + ks * 16);
                short8 a0 = *(const short8*)(wa + ks * 16);
                short8 a1 = *(const short8*)(wa + 32 * 128 + ks * 16);
                acc0 = MFMA32(a0, bv, acc0);
                acc1 = MFMA32(a1, bv, acc1);
            }
        }
    }
    float ls = 0.f;
    bool wr = (wv >> 1) == 0 || lrow >= 8;
    if (wr) {
        #pragma unroll
        for (int mf = 0; mf < 2; ++mf) {
            #pragma unroll
            for (int reg = 0; reg < 16; ++reg) {
                int co = m0 + mf * 32 + (reg & 3) + 8 * (reg >> 2) + 4 * khalf;
                float z = (mf ? acc1[reg] : acc0[reg]) + bias[co];
                float d = c[co] - z;
                ls += d * d;
            }
        }
    }
    #pragma unroll
    for (int off = 32; off > 0; off >>= 1) ls += __shfl_down(ls, off);
    if (lane == 0) red[wv] = ls;
    __syncthreads();
    if (tid == 0) vq_part[b * 56 + oh] = red[0] + red[1] + red[2] + red[3];
}

// ---------------- decoder class-table path (z_q spatially constant) ----------------
// k_SD3: S[co][kh][kw] = sum_ci w_d1*c; D3[co][rh][rw] = b_d1 + sum of in-range taps
__global__ __launch_bounds__(128) void k_SD3(const float* __restrict__ w_d1,
                                             const float* __restrict__ c,
                                             const float* __restrict__ b_d1,
                                             float* __restrict__ D3) {
    int co = blockIdx.x, ci = threadIdx.x;
    __shared__ float cl[128];
    __shared__ float part[9][128];
    cl[ci] = c[ci];
    __syncthreads();
    const float* wp = w_d1 + (co * 128 + ci) * 9;
    float cv = cl[ci];
    #pragma unroll
    for (int t = 0; t < 9; ++t) part[t][ci] = wp[t] * cv;
    __syncthreads();
    for (int off = 64; off > 0; off >>= 1) {
        if (ci < off) {
            #pragma unroll
            for (int t = 0; t < 9; ++t) part[t][ci] += part[t][ci + off];
        }
        __syncthreads();
    }
    if (ci < 9) {
        int rh = ci / 3, rw = ci % 3;
        int kh0 = (rh == 0) ? 1 : 0, kh1 = (rh == 2) ? 1 : 2;
        int kw0 = (rw == 0) ? 1 : 0, kw1 = (rw == 2) ? 1 : 2;
        float a = b_d1[co];
        for (int kh = kh0; kh <= kh1; ++kh)
            for (int kw = kw0; kw <= kw1; ++kw)
                a += part[kh * 3 + kw][0];
        D3[co * 9 + ci] = a;
    }
}

// k_d2c: d2 class values [gh8][gw8][co2 64] = relu(convT1 of D3 at representative pos)
__global__ __launch_bounds__(64) void k_d2c(const float* __restrict__ D3,
                                            const float* __restrict__ w_dt1,
                                            const float* __restrict__ b_dt1,
                                            float* __restrict__ d2c) {
    __shared__ float dl[1152];
    int gh = blockIdx.x, gw = blockIdx.y, co2 = threadIdx.x;
    for (int i = co2; i < 1152; i += 64) dl[i] = D3[i];
    __syncthreads();
    const int rep[8] = {0, 1, 2, 4, 3, 109, 110, 111};
    int oh = rep[gh], ow = rep[gw];
    float a = b_dt1[co2];
    #pragma unroll
    for (int th = 0; th < 2; ++th) {
        int kh = ((oh + 1) & 1) + 2 * th;
        int ih = (oh + 1 - kh) >> 1;
        if ((unsigned)ih >= 56u) continue;
        int rh = (ih == 0) ? 0 : (ih == 55) ? 2 : 1;
        #pragma unroll
        for (int tw = 0; tw < 2; ++tw) {
            int kw = ((ow + 1) & 1) + 2 * tw;
            int iw = (ow + 1 - kw) >> 1;
            if ((unsigned)iw >= 56u) continue;
            int rw = (iw == 0) ? 0 : (iw == 55) ? 2 : 1;
            float t = 0.f;
            for (int ci = 0; ci < 128; ++ci)
                t += dl[ci * 9 + rh * 3 + rw] * w_dt1[(ci * 64 + co2) * 16 + kh * 4 + kw];
            a += t;
        }
    }
    d2c[(gh * 8 + gw) * 64 + co2] = fmaxf(a, 0.f);
}

// k_Rbuild: e[kh][kw][gh][gw] = sum_ci d2c*w_dt2 (per-block in LDS), then R from classes
__global__ __launch_bounds__(256) void k_Rbuild(const float* __restrict__ d2c,
                                                const float* __restrict__ w_dt2,
                                                const float* __restrict__ b_dt2,
                                                float* __restrict__ R) {
    __shared__ float el[1024];
    int tid = threadIdx.x;
    #pragma unroll
    for (int q = 0; q < 4; ++q) {
        int id = tid * 4 + q;
        int kh = id >> 8, kw = (id >> 6) & 3, gh = (id >> 3) & 7, gw = id & 7;
        float t = 0.f;
        const float* dp = d2c + (gh * 8 + gw) * 64;
        const float* wp = w_dt2 + kh * 4 + kw;
        for (int ci = 0; ci < 64; ++ci) t += dp[ci] * wp[ci * 16];
        el[((kh * 4 + kw) * 8 + gh) * 8 + gw] = t;
    }
    __syncthreads();
    int s = blockIdx.x * 256 + tid;
    int oh = s / 224, ow = s % 224;
    float a = b_dt2[0];
    #pragma unroll
    for (int th = 0; th < 2; ++th) {
        int kh = ((oh + 1) & 1) + 2 * th;
        int ih = (oh + 1 - kh) >> 1;
        if ((unsigned)ih >= 112u) continue;
        int ch = cls8(ih);
        #pragma unroll
        for (int tw = 0; tw < 2; ++tw) {
            int kw = ((ow + 1) & 1) + 2 * tw;
            int iw = (ow + 1 - kw) >> 1;
            if ((unsigned)iw >= 112u) continue;
            int cw = cls8(iw);
            a += el[((kh * 4 + kw) * 8 + ch) * 8 + cw];
        }
    }
    R[s] = a;
}

// ---------------- replicate R into out, rec-loss partials ----------------
__global__ __launch_bounds__(256) void k_out(const float* __restrict__ R,
                                             const float* __restrict__ x,
                                             float* __restrict__ out,
                                             float* __restrict__ rec_part) {
    int idx = blockIdx.x * 256 + threadIdx.x;
    int s = idx % 50176;
    float r = R[s];
    out[idx] = r;
    float df = r - x[idx];
    float v = df * df;
    __shared__ float red[4];
    #pragma unroll
    for (int off = 32; off > 0; off >>= 1) v += __shfl_down(v, off);
    int wid = threadIdx.x >> 6, lane = threadIdx.x & 63;
    if (lane == 0) red[wid] = v;
    __syncthreads();
    if (threadIdx.x == 0) rec_part[blockIdx.x] = red[0] + red[1] + red[2] + red[3];
}

__global__ __launch_bounds__(256) void k_fin(const float* __restrict__ vq_part,
                                             const float* __restrict__ rec_part,
                                             float* __restrict__ out, int loss_base) {
    __shared__ float sv[256], sr[256];
    float a = 0.f, b2 = 0.f;
    for (int i = threadIdx.x; i < 1792; i += 256) a  += vq_part[i];
    for (int i = threadIdx.x; i < 6272; i += 256) b2 += rec_part[i];
    sv[threadIdx.x] = a; sr[threadIdx.x] = b2;
    __syncthreads();
    for (int off = 128; off > 0; off >>= 1) {
        if (threadIdx.x < off) { sv[threadIdx.x] += sv[threadIdx.x + off]; sr[threadIdx.x] += sr[threadIdx.x + off]; }
        __syncthreads();
    }
    if (threadIdx.x == 0) {
        float vq  = 2.f * sv[0] / 12845056.f;
        float rec = sr[0] / 1605632.f;
        out[loss_base + 0] = rec + vq;
        out[loss_base + 1] = rec;
        out[loss_base + 2] = vq;
    }
}

extern "C" void kernel_launch(void* const* d_in, const int* in_sizes, int n_in,
                              void* d_out, int out_size, void* d_ws, size_t ws_size,
                              hipStream_t stream) {
    const float* x     = (const float*)d_in[0];
    const float* w_e1  = (const float*)d_in[1];
    const float* b_e1  = (const float*)d_in[2];
    const float* w_e2  = (const float*)d_in[3];
    const float* b_e2  = (const float*)d_in[4];
    const float* w_e3  = (const float*)d_in[5];
    const float* b_e3  = (const float*)d_in[6];
    const float* emb   = (const float*)d_in[7];
    const float* w_d1  = (const float*)d_in[8];
    const float* b_d1  = (const float*)d_in[9];
    const float* w_dt1 = (const float*)d_in[10];
    const float* b_dt1 = (const float*)d_in[11];
    const float* w_dt2 = (const float*)d_in[12];
    const float* b_dt2 = (const float*)d_in[13];
    float* out = (float*)d_out;
    float* ws  = (float*)d_ws;

    // ws layout (float offsets)
    float* c        = ws + 16;       // 128
    float* D3       = ws + 256;      // 1152
    float* d2c      = ws + 2048;     // 4096
    float* R        = ws + 8192;     // 50176
    float* vq_part  = ws + 65536;    // 1792
    float* rec_part = ws + 67584;    // 6272
    ushort* Wb2     = (ushort*)(ws + 131072);   // 131072 us
    ushort* Wb3     = (ushort*)(ws + 196608);   // 147456 us
    ushort* h1q     = (ushort*)(ws + 1310720);  // 25,690,112 us
    ushort* h2      = (ushort*)(ws + 14155776); // 12,845,056 us

    k_codebook<<<1, 512, 0, stream>>>(emb, c);
    k_prepack<<<1088, 256, 0, stream>>>(w_e2, w_e3, Wb2, Wb3);
    k_conv1<<<dim3(25, 2, 32), 256, 0, stream>>>(x, w_e1, b_e1, h1q);
    k_conv2_mfma<<<dim3(56, 32), 256, 0, stream>>>(h1q, Wb2, b_e2, h2);
    k_conv3_mfma<<<dim3(56, 32), 256, 0, stream>>>(h2, Wb3, b_e3, c, vq_part);
    k_SD3<<<128, 128, 0, stream>>>(w_d1, c, b_d1, D3);
    k_d2c<<<dim3(8, 8), 64, 0, stream>>>(D3, w_dt1, b_dt1, d2c);
    k_Rbuild<<<196, 256, 0, stream>>>(d2c, w_dt2, b_dt2, R);
    k_out<<<6272, 256, 0, stream>>>(R, x, out, rec_part);
    k_fin<<<1, 256, 0, stream>>>(vq_part, rec_part, out, out_size - 3);
}